// Round 4
// baseline (397.617 us; speedup 1.0000x reference)
//
#include <hip/hip_runtime.h>
#include <math.h>

typedef float f32x16 __attribute__((ext_vector_type(16)));
typedef short bf16x8 __attribute__((ext_vector_type(8)));
typedef short bf16x4 __attribute__((ext_vector_type(4)));
typedef unsigned short u16;
typedef unsigned int u32;

#define MFMA32(a, b, c) __builtin_amdgcn_mfma_f32_32x32x16_bf16(a, b, c, 0, 0, 0)

__device__ __forceinline__ u16 f2bf(float x) {
    u32 u = __float_as_uint(x);
    u += 0x7FFFu + ((u >> 16) & 1u);
    return (u16)(u >> 16);
}
__device__ __forceinline__ float bf2f(u16 h) {
    return __uint_as_float(((u32)h) << 16);
}

// ---------------------------------------------------------------------------
// prep with rank-factorized q/k: score_vec = sum_c m_c * vq_c^T (Wq^T Wk) uk_c
//   q embed (64 dims) = normalized vecs * SC        (wave0, + V features)
//   k embed (64 dims) = metric-folded G @ u, G=Wq^T Wk (wave1, G on device)
//   scalar embeds (64 dims, offset 64)              (waves 2/3)
// Outputs: qh/ql/kh/kl token-major [tok][128] bf16 hi/lo; vth/vtl [b][dv][1024].
// ---------------------------------------------------------------------------
__global__ __launch_bounds__(256) void prep_kernel(
    const float* __restrict__ vectors, const float* __restrict__ scalars,
    const float* __restrict__ Wq, const float* __restrict__ Wq_s, const float* __restrict__ bq_s,
    const float* __restrict__ Wk, const float* __restrict__ Wk_s, const float* __restrict__ bk_s,
    const float* __restrict__ Wv,
    u16* __restrict__ qh, u16* __restrict__ ql,
    u16* __restrict__ kh, u16* __restrict__ kl,
    u16* __restrict__ vth, u16* __restrict__ vtl)
{
    __shared__ float vl[64 * 68];    // normalized vectors [tok][64]
    __shared__ float sl[64 * 68];    // scalars [tok][64]
    __shared__ u32 vst[64 * 65];     // v staging [dv][tok], hi | lo<<16
    __shared__ float wls[1024];      // Wq (512) | Wk (512) for G

    const int t = threadIdx.x;
    const int lane = t & 63;
    const int w = t >> 6;
    const int b = blockIdx.x >> 4;
    const int n0 = (blockIdx.x & 15) << 6;
    const long tok0 = (long)b * 1024 + n0;

    // ---- stage inputs + weights ----
    const float4* vin = (const float4*)(vectors + tok0 * 64);
    const float4* sin4 = (const float4*)(scalars + tok0 * 64);
#pragma unroll
    for (int r = 0; r < 4; ++r) {
        int i4 = t + (r << 8);
        int tok = i4 >> 4, c4 = (i4 & 15) << 2;
        *(float4*)&vl[tok * 68 + c4] = vin[i4];
        *(float4*)&sl[tok * 68 + c4] = sin4[i4];
    }
    for (int i = t; i < 1024; i += 256) wls[i] = (i < 512) ? Wq[i] : Wk[i - 512];

    float wrv[16];
    float wsr[64];
    float bias = 0.f;
    if (w == 0) {
#pragma unroll
        for (int j = 0; j < 16; ++j) wrv[j] = expf(Wv[(lane >> 2) * 16 + j]);
    } else if (w == 2) {
#pragma unroll
        for (int c4 = 0; c4 < 16; ++c4) {
            float4 x = *(const float4*)(Wq_s + lane * 64 + c4 * 4);
            wsr[c4 * 4 + 0] = x.x; wsr[c4 * 4 + 1] = x.y;
            wsr[c4 * 4 + 2] = x.z; wsr[c4 * 4 + 3] = x.w;
        }
        bias = bq_s[lane];
    } else if (w == 3) {
#pragma unroll
        for (int c4 = 0; c4 < 16; ++c4) {
            float4 x = *(const float4*)(Wk_s + lane * 64 + c4 * 4);
            wsr[c4 * 4 + 0] = x.x; wsr[c4 * 4 + 1] = x.y;
            wsr[c4 * 4 + 2] = x.z; wsr[c4 * 4 + 3] = x.w;
        }
        bias = bk_s[lane];
    }
    __syncthreads();

    // ---- Lorentz normalize in place ----
#pragma unroll
    for (int r = 0; r < 4; ++r) {
        int gi = t + (r << 8);
        float* p = &vl[(gi >> 4) * 68 + ((gi & 15) << 2)];
        float x0 = p[0], x1 = p[1], x2 = p[2], x3 = p[3];
        float nrm = x0 * x0 - x1 * x1 - x2 * x2 - x3 * x3;
        float inv = 1.0f / sqrtf(fmaxf(fabsf(nrm), 1e-5f));
        p[0] = x0 * inv; p[1] = x1 * inv; p[2] = x2 * inv; p[3] = x3 * inv;
    }
    __syncthreads();

    const float SC = 0.07216878364870323f;   // 1/sqrt(192)

    if (w == 0) {
        // q embed = normalized vec * SC (feature = lane); V feature = lane
        const int kc = lane & 3;
        for (int tp = 0; tp < 64; tp += 2) {
            float q0 = vl[tp * 68 + lane] * SC;
            float q1 = vl[tp * 68 + 68 + lane] * SC;
            u16 q0h = f2bf(q0), q1h = f2bf(q1);
            u16 q0l = f2bf(q0 - bf2f(q0h)), q1l = f2bf(q1 - bf2f(q1h));
            long o_ = (tok0 + tp) * 128 + lane;
            qh[o_] = q0h; ql[o_] = q0l;
            qh[o_ + 128] = q1h; ql[o_ + 128] = q1l;
            float a0 = 0.f, a1 = 0.f;
            const float* p0 = &vl[tp * 68 + kc];
#pragma unroll
            for (int j = 0; j < 16; ++j) {
                a0 = fmaf(wrv[j], p0[j * 4], a0);
                a1 = fmaf(wrv[j], p0[68 + j * 4], a1);
            }
            u16 h0 = f2bf(a0), h1 = f2bf(a1);
            vst[lane * 65 + tp]     = (u32)h0 | ((u32)f2bf(a0 - bf2f(h0)) << 16);
            vst[lane * 65 + tp + 1] = (u32)h1 | ((u32)f2bf(a1 - bf2f(h1)) << 16);
        }
    } else if (w == 1) {
        // k embed: G = Wq^T Wk (row j per lane-group), metric folded into gr
        const int j = lane >> 2, c = lane & 3;
        const float mc = (c == 0) ? 1.f : -1.f;
        float wqc[32];
#pragma unroll
        for (int i = 0; i < 32; ++i) wqc[i] = wls[i * 16 + j];
        float gr[16];
#pragma unroll
        for (int jp = 0; jp < 16; ++jp) {
            float acc0 = 0.f, acc1 = 0.f;
#pragma unroll
            for (int i = 0; i < 32; i += 2) {
                acc0 = fmaf(wqc[i],     wls[512 + i * 16 + jp], acc0);
                acc1 = fmaf(wqc[i + 1], wls[512 + (i + 1) * 16 + jp], acc1);
            }
            gr[jp] = (acc0 + acc1) * mc;
        }
        for (int tp = 0; tp < 64; tp += 2) {
            float a0 = 0.f, a1 = 0.f;
            const float* p0 = &vl[tp * 68 + c];
#pragma unroll
            for (int jp = 0; jp < 16; ++jp) {
                a0 = fmaf(gr[jp], p0[jp * 4], a0);
                a1 = fmaf(gr[jp], p0[68 + jp * 4], a1);
            }
            u16 h0 = f2bf(a0), h1 = f2bf(a1);
            u16 l0_ = f2bf(a0 - bf2f(h0)), l1_ = f2bf(a1 - bf2f(h1));
            long o_ = (tok0 + tp) * 128 + lane;
            kh[o_] = h0; kl[o_] = l0_;
            kh[o_ + 128] = h1; kl[o_ + 128] = l1_;
        }
    } else {
        // scalar features (offset 64): wave2 q (scaled), wave3 k
        const int isq = (w == 2);
        u16* oh = isq ? qh : kh;
        u16* ol = isq ? ql : kl;
        const float sc = isq ? SC : 1.f;
        for (int tp = 0; tp < 64; tp += 2) {
            const float* s0 = &sl[tp * 68];
            const float* s1 = s0 + 68;
            float a00 = 0.f, a01 = 0.f, a10 = 0.f, a11 = 0.f;
#pragma unroll
            for (int c4 = 0; c4 < 16; c4 += 2) {
                float4 x0 = *(const float4*)(s0 + c4 * 4);
                float4 y0 = *(const float4*)(s0 + c4 * 4 + 4);
                float4 x1 = *(const float4*)(s1 + c4 * 4);
                float4 y1 = *(const float4*)(s1 + c4 * 4 + 4);
                a00 = fmaf(wsr[c4*4+0], x0.x, a00); a00 = fmaf(wsr[c4*4+1], x0.y, a00);
                a00 = fmaf(wsr[c4*4+2], x0.z, a00); a00 = fmaf(wsr[c4*4+3], x0.w, a00);
                a01 = fmaf(wsr[c4*4+4], y0.x, a01); a01 = fmaf(wsr[c4*4+5], y0.y, a01);
                a01 = fmaf(wsr[c4*4+6], y0.z, a01); a01 = fmaf(wsr[c4*4+7], y0.w, a01);
                a10 = fmaf(wsr[c4*4+0], x1.x, a10); a10 = fmaf(wsr[c4*4+1], x1.y, a10);
                a10 = fmaf(wsr[c4*4+2], x1.z, a10); a10 = fmaf(wsr[c4*4+3], x1.w, a10);
                a11 = fmaf(wsr[c4*4+4], y1.x, a11); a11 = fmaf(wsr[c4*4+5], y1.y, a11);
                a11 = fmaf(wsr[c4*4+6], y1.z, a11); a11 = fmaf(wsr[c4*4+7], y1.w, a11);
            }
            float a0 = (a00 + a01 + bias) * sc;
            float a1 = (a10 + a11 + bias) * sc;
            u16 h0 = f2bf(a0), h1 = f2bf(a1);
            u16 l0_ = f2bf(a0 - bf2f(h0)), l1_ = f2bf(a1 - bf2f(h1));
            long o_ = (tok0 + tp) * 128 + 64 + lane;
            oh[o_] = h0; ol[o_] = l0_;
            oh[o_ + 128] = h1; ol[o_ + 128] = l1_;
        }
    }
    __syncthreads();

    // ---- coalesced v copy-out ----
#pragma unroll
    for (int r = 0; r < 16; ++r) {
        int i = t + (r << 8);
        int dv = i >> 6, tok = i & 63;
        u32 p = vst[dv * 65 + tok];
        long o = ((long)b * 64 + dv) * 1024 + n0 + tok;
        vth[o] = (u16)(p & 0xFFFFu);
        vtl[o] = (u16)(p >> 16);
    }
}

// ---------------------------------------------------------------------------
// MFMA flash attention, d_qk = 128. QK: 3 hi/lo passes (24 MFMA);
// PV: 2 passes ph*vh + ph*vl (8 MFMA); defer-max rescale; odd-dword LDS
// pitches (134/42) for conflict-free reads.
// ---------------------------------------------------------------------------
__global__ __launch_bounds__(256, 2) void attn_kernel(
    const u16* __restrict__ qh, const u16* __restrict__ ql,
    const u16* __restrict__ kh, const u16* __restrict__ kl,
    const u16* __restrict__ vth, const u16* __restrict__ vtl,
    float* __restrict__ out)
{
    __shared__ u16 KH[2 * 32 * 134];
    __shared__ u16 KL[2 * 32 * 134];
    __shared__ u16 VH[2 * 64 * 42];
    __shared__ u16 VL[2 * 64 * 42];

    const int t = threadIdx.x;
    const int lane = t & 63;
    const int w = t >> 6;
    const int l31 = lane & 31, g = lane >> 5;

    const int bid = blockIdx.x;
    const int b = ((bid & 7) << 3) + (bid >> 6);
    const int qt = (bid >> 3) & 7;

    const long qtok = (long)b * 1024 + qt * 128 + w * 32 + l31;
    const u16* qhp = qh + qtok * 128 + g * 8;
    const u16* qlp = ql + qtok * 128 + g * 8;
    bf16x8 Qh[8], Ql[8];
#pragma unroll
    for (int c = 0; c < 8; ++c) {
        Qh[c] = *(const bf16x8*)(qhp + c * 16);
        Ql[c] = *(const bf16x8*)(qlp + c * 16);
    }

    const int skk = t >> 3, scs = t & 7;
    const u16* kh_g = kh + ((long)b * 1024 + skk) * 128 + scs * 16;
    const u16* kl_g = kl + ((long)b * 1024 + skk) * 128 + scs * 16;
    const int sdv = t >> 2, ssg = t & 3;
    const u16* vh_g = vth + ((long)b * 64 + sdv) * 1024 + ssg * 8;
    const u16* vl_g = vtl + ((long)b * 64 + sdv) * 1024 + ssg * 8;
    u16* kh_d = KH + skk * 134 + scs * 16;
    u16* kl_d = KL + skk * 134 + scs * 16;
    u16* vh_d = VH + sdv * 42 + ssg * 8;
    u16* vl_d = VL + sdv * 42 + ssg * 8;

    int4 ra0, ra1, rb0, rb1, rc0, rd0;

#define LOADT(kt) do { \
        const u16* p1 = kh_g + (long)(kt) * 128; \
        ra0 = *(const int4*)(p1); ra1 = *(const int4*)(p1 + 8); \
        const u16* p2 = kl_g + (long)(kt) * 128; \
        rb0 = *(const int4*)(p2); rb1 = *(const int4*)(p2 + 8); \
        rc0 = *(const int4*)(vh_g + (kt)); \
        rd0 = *(const int4*)(vl_g + (kt)); \
    } while (0)

#define WRITET(buf) do { \
        u16* d1 = kh_d + (buf) * 4288; \
        *(int4*)(d1) = ra0; *(int4*)(d1 + 8) = ra1; \
        u16* d2 = kl_d + (buf) * 4288; \
        *(int4*)(d2) = rb0; *(int4*)(d2 + 8) = rb1; \
        *(int4*)(vh_d + (buf) * 2688) = rc0; \
        *(int4*)(vl_d + (buf) * 2688) = rd0; \
    } while (0)

    f32x16 o0, o1;
#pragma unroll
    for (int r = 0; r < 16; ++r) { o0[r] = 0.f; o1[r] = 0.f; }
    float m_run = -1e30f, l_run = 0.f;

    LOADT(0);
    WRITET(0);
    __syncthreads();

    for (int it = 0; it < 32; ++it) {
        const int cb = it & 1;
        if (it < 31) LOADT((it + 1) * 32);

        f32x16 sA, sB;
#pragma unroll
        for (int r = 0; r < 16; ++r) { sA[r] = 0.f; sB[r] = 0.f; }
        const u16* krh = KH + cb * 4288 + l31 * 134 + g * 8;
        const u16* krl = KL + cb * 4288 + l31 * 134 + g * 8;
        __builtin_amdgcn_s_setprio(1);
#pragma unroll
        for (int c = 0; c < 8; ++c) {
            bf16x8 fh = *(const bf16x8*)(krh + c * 16);
            bf16x8 fl = *(const bf16x8*)(krl + c * 16);
            sA = MFMA32(fh, Qh[c], sA);
            sB = MFMA32(fh, Ql[c], sB);
            sB = MFMA32(fl, Qh[c], sB);
        }
        __builtin_amdgcn_s_setprio(0);

        float s[16];
#pragma unroll
        for (int r = 0; r < 16; ++r) s[r] = sA[r] + sB[r];
        float mt = s[0];
#pragma unroll
        for (int r = 1; r < 16; ++r) mt = fmaxf(mt, s[r]);
        mt = fmaxf(mt, __shfl_xor(mt, 32));
        if (!__all(mt - m_run <= 8.f)) {
            float mn = fmaxf(m_run, mt);
            float corr = __expf(m_run - mn);
            l_run *= corr;
#pragma unroll
            for (int r = 0; r < 16; ++r) { o0[r] *= corr; o1[r] *= corr; }
            m_run = mn;
        }
        float ps = 0.f;
#pragma unroll
        for (int r = 0; r < 16; ++r) { s[r] = __expf(s[r] - m_run); ps += s[r]; }
        ps += __shfl_xor(ps, 32);
        l_run += ps;

        bf16x8 ph0, ph1;
#pragma unroll
        for (int e = 0; e < 8; ++e) {
            ph0[e] = (short)f2bf(s[e]);
            ph1[e] = (short)f2bf(s[8 + e]);
        }

        const u16* vbh = VH + cb * 2688;
        const u16* vbl = VL + cb * 2688;
        __builtin_amdgcn_s_setprio(1);
#pragma unroll
        for (int d = 0; d < 2; ++d) {
            f32x16 acc = d ? o1 : o0;
#pragma unroll
            for (int c = 0; c < 2; ++c) {
                const u16* ph_ = vbh + (d * 32 + l31) * 42 + c * 16 + g * 4;
                const u16* pl_ = vbl + (d * 32 + l31) * 42 + c * 16 + g * 4;
                bf16x4 h0 = *(const bf16x4*)(ph_);
                bf16x4 h1 = *(const bf16x4*)(ph_ + 8);
                bf16x4 l0 = *(const bf16x4*)(pl_);
                bf16x4 l1 = *(const bf16x4*)(pl_ + 8);
                bf16x8 vh8 = __builtin_shufflevector(h0, h1, 0, 1, 2, 3, 4, 5, 6, 7);
                bf16x8 vl8 = __builtin_shufflevector(l0, l1, 0, 1, 2, 3, 4, 5, 6, 7);
                bf16x8 pc = c ? ph1 : ph0;
                acc = MFMA32(vh8, pc, acc);
                acc = MFMA32(vl8, pc, acc);
            }
            if (d) o1 = acc; else o0 = acc;
        }
        __builtin_amdgcn_s_setprio(0);

        if (it < 31) WRITET(cb ^ 1);
        __syncthreads();
    }

    float inv = 1.0f / l_run;
    float* op = out + qtok * 64;
#pragma unroll
    for (int d = 0; d < 2; ++d) {
#pragma unroll
        for (int sg = 0; sg < 4; ++sg) {
            float4 o4;
            if (d == 0) o4 = make_float4(o0[4*sg+0]*inv, o0[4*sg+1]*inv, o0[4*sg+2]*inv, o0[4*sg+3]*inv);
            else        o4 = make_float4(o1[4*sg+0]*inv, o1[4*sg+1]*inv, o1[4*sg+2]*inv, o1[4*sg+3]*inv);
            *(float4*)(op + d * 32 + sg * 8 + g * 4) = o4;
        }
    }
#undef LOADT
#undef WRITET
}

extern "C" void kernel_launch(void* const* d_in, const int* in_sizes, int n_in,
                              void* d_out, int out_size, void* d_ws, size_t ws_size,
                              hipStream_t stream) {
    const float* vectors = (const float*)d_in[0];
    const float* scalars = (const float*)d_in[1];
    const float* Wq   = (const float*)d_in[2];
    const float* Wq_s = (const float*)d_in[3];
    const float* bq_s = (const float*)d_in[4];
    const float* Wk   = (const float*)d_in[5];
    const float* Wk_s = (const float*)d_in[6];
    const float* bk_s = (const float*)d_in[7];
    const float* Wv   = (const float*)d_in[8];
    float* o = (float*)d_out;

    u16* qh  = (u16*)d_ws;                 // 64*1024*128 each
    u16* ql  = qh + 8388608;
    u16* kh  = ql + 8388608;
    u16* kl  = kh + 8388608;
    u16* vth = kl + 8388608;               // 64*64*1024 each
    u16* vtl = vth + 4194304;

    prep_kernel<<<1024, 256, 0, stream>>>(vectors, scalars, Wq, Wq_s, bq_s,
                                          Wk, Wk_s, bk_s, Wv,
                                          qh, ql, kh, kl, vth, vtl);
    attn_kernel<<<512, 256, 0, stream>>>(qh, ql, kh, kl, vth, vtl, o);
}

// Round 5
// 181.961 us; speedup vs baseline: 2.1852x; 2.1852x over previous
//
#include <hip/hip_runtime.h>
#include <math.h>

typedef float f32x16 __attribute__((ext_vector_type(16)));
typedef short bf16x8 __attribute__((ext_vector_type(8)));
typedef short bf16x4 __attribute__((ext_vector_type(4)));
typedef unsigned short u16;
typedef unsigned int u32;

#define MFMA32(a, b, c) __builtin_amdgcn_mfma_f32_32x32x16_bf16(a, b, c, 0, 0, 0)

__device__ __forceinline__ u16 f2bf(float x) {
    u32 u = __float_as_uint(x);
    u += 0x7FFFu + ((u >> 16) & 1u);
    return (u16)(u >> 16);
}
__device__ __forceinline__ float bf2f(u16 h) {
    return __uint_as_float(((u32)h) << 16);
}
__device__ __forceinline__ u32 packhl(float x) {
    u16 h = f2bf(x);
    u16 l = f2bf(x - bf2f(h));
    return (u32)h | ((u32)l << 16);
}

// ---------------------------------------------------------------------------
// prep, rank-factorized: score_vec = sum_c m_c * (SC*v_q[:,c])^T G u_k[:,c],
// G = Wq^T Wk (16x16, computed by wave1 once).
//   wave0: q vec feats (trivial copy*SC) + V feats -> vst
//   wave1: k vec feats = m_c * G[i,:]·u[:,c]
//   wave2/3: q/k scalar feats (weights in regs, scalars read direct global)
// Outputs: qhl/khl u32 planes [tok][128] (hi|lo<<16); vth/vtl [b][dv][1024].
// ---------------------------------------------------------------------------
__global__ __launch_bounds__(256, 3) void prep_kernel(
    const float* __restrict__ vectors, const float* __restrict__ scalars,
    const float* __restrict__ Wq, const float* __restrict__ Wq_s, const float* __restrict__ bq_s,
    const float* __restrict__ Wk, const float* __restrict__ Wk_s, const float* __restrict__ bk_s,
    const float* __restrict__ Wv,
    u32* __restrict__ qhl, u32* __restrict__ khl,
    u16* __restrict__ vth, u16* __restrict__ vtl)
{
    __shared__ float vl[64 * 68];    // normalized vectors [tok][64]
    __shared__ u32 vst[64 * 65];     // v staging [dv][tok], hi|lo<<16
    __shared__ float wls[1024];      // Wq (512) | Wk (512)

    const int t = threadIdx.x;
    const int lane = t & 63;
    const int w = t >> 6;
    const int b = blockIdx.x >> 4;
    const int n0 = (blockIdx.x & 15) << 6;
    const long tok0 = (long)b * 1024 + n0;

    // ---- stage vectors + weight LDS ----
    const float4* vin = (const float4*)(vectors + tok0 * 64);
#pragma unroll
    for (int r = 0; r < 4; ++r) {
        int i4 = t + (r << 8);
        int tok = i4 >> 4, c4 = (i4 & 15) << 2;
        *(float4*)&vl[tok * 68 + c4] = vin[i4];
    }
    for (int i = t; i < 1024; i += 256) wls[i] = (i < 512) ? Wq[i] : Wk[i - 512];

    float wrv[16];
    float wsr[64];
    float bias = 0.f;
    if (w == 0) {
#pragma unroll
        for (int j = 0; j < 16; ++j) wrv[j] = expf(Wv[(lane >> 2) * 16 + j]);
    } else if (w == 2) {
#pragma unroll
        for (int c4 = 0; c4 < 16; ++c4) {
            float4 x = *(const float4*)(Wq_s + lane * 64 + c4 * 4);
            wsr[c4 * 4 + 0] = x.x; wsr[c4 * 4 + 1] = x.y;
            wsr[c4 * 4 + 2] = x.z; wsr[c4 * 4 + 3] = x.w;
        }
        bias = bq_s[lane];
    } else if (w == 3) {
#pragma unroll
        for (int c4 = 0; c4 < 16; ++c4) {
            float4 x = *(const float4*)(Wk_s + lane * 64 + c4 * 4);
            wsr[c4 * 4 + 0] = x.x; wsr[c4 * 4 + 1] = x.y;
            wsr[c4 * 4 + 2] = x.z; wsr[c4 * 4 + 3] = x.w;
        }
        bias = bk_s[lane];
    }
    __syncthreads();

    // ---- Lorentz normalize in place ----
#pragma unroll
    for (int r = 0; r < 4; ++r) {
        int gi = t + (r << 8);
        float* p = &vl[(gi >> 4) * 68 + ((gi & 15) << 2)];
        float x0 = p[0], x1 = p[1], x2 = p[2], x3 = p[3];
        float nrm = x0 * x0 - x1 * x1 - x2 * x2 - x3 * x3;
        float inv = 1.0f / sqrtf(fmaxf(fabsf(nrm), 1e-5f));
        p[0] = x0 * inv; p[1] = x1 * inv; p[2] = x2 * inv; p[3] = x3 * inv;
    }
    __syncthreads();

    const float SC = 0.07216878364870323f;   // 1/sqrt(192)

    if (w == 0) {
        // q vec feature = lane (just normalized vec * SC); V feature = lane
        const int vc = lane & 3;
        for (int tok = 0; tok < 64; ++tok) {
            qhl[(tok0 + tok) * 128 + lane] = packhl(vl[tok * 68 + lane] * SC);
            const float* p0 = &vl[tok * 68 + vc];
            float a0 = 0.f, a1 = 0.f, a2 = 0.f, a3 = 0.f;
#pragma unroll
            for (int j = 0; j < 16; j += 4) {
                a0 = fmaf(wrv[j],     p0[j * 4],       a0);
                a1 = fmaf(wrv[j + 1], p0[(j + 1) * 4], a1);
                a2 = fmaf(wrv[j + 2], p0[(j + 2) * 4], a2);
                a3 = fmaf(wrv[j + 3], p0[(j + 3) * 4], a3);
            }
            vst[lane * 65 + tok] = packhl((a0 + a1) + (a2 + a3));
        }
    } else if (w == 1) {
        // G row: gr[jp] = m_c * sum_f Wq[f,i]*Wk[f,jp]
        const int i_ = lane >> 2, c = lane & 3;
        const float mc = (c == 0) ? 1.f : -1.f;
        float wqc[32];
#pragma unroll
        for (int f = 0; f < 32; ++f) wqc[f] = wls[f * 16 + i_];
        float gr[16];
#pragma unroll
        for (int jp = 0; jp < 16; ++jp) {
            float a0 = 0.f, a1 = 0.f;
#pragma unroll
            for (int f = 0; f < 32; f += 2) {
                a0 = fmaf(wqc[f],     wls[512 + f * 16 + jp],       a0);
                a1 = fmaf(wqc[f + 1], wls[512 + (f + 1) * 16 + jp], a1);
            }
            gr[jp] = (a0 + a1) * mc;
        }
        for (int tok = 0; tok < 64; ++tok) {
            const float* p0 = &vl[tok * 68 + c];
            float a0 = 0.f, a1 = 0.f, a2 = 0.f, a3 = 0.f;
#pragma unroll
            for (int jp = 0; jp < 16; jp += 4) {
                a0 = fmaf(gr[jp],     p0[jp * 4],       a0);
                a1 = fmaf(gr[jp + 1], p0[(jp + 1) * 4], a1);
                a2 = fmaf(gr[jp + 2], p0[(jp + 2) * 4], a2);
                a3 = fmaf(gr[jp + 3], p0[(jp + 3) * 4], a3);
            }
            khl[(tok0 + tok) * 128 + lane] = packhl((a0 + a1) + (a2 + a3));
        }
    } else {
        // scalar features 64+lane (w2: q scaled, w3: k), scalars direct global
        const int isq = (w == 2);
        u32* oplane = isq ? qhl : khl;
        const float sc = isq ? SC : 1.f;
        for (int tok = 0; tok < 64; ++tok) {
            const float* sp = scalars + (tok0 + tok) * 64;
            float a0 = 0.f, a1 = 0.f, a2 = 0.f, a3 = 0.f;
#pragma unroll
            for (int c4 = 0; c4 < 16; ++c4) {
                float4 x = *(const float4*)(sp + c4 * 4);
                a0 = fmaf(wsr[c4 * 4 + 0], x.x, a0);
                a1 = fmaf(wsr[c4 * 4 + 1], x.y, a1);
                a2 = fmaf(wsr[c4 * 4 + 2], x.z, a2);
                a3 = fmaf(wsr[c4 * 4 + 3], x.w, a3);
            }
            float a = ((a0 + a1) + (a2 + a3) + bias) * sc;
            oplane[(tok0 + tok) * 128 + 64 + lane] = packhl(a);
        }
    }
    __syncthreads();

    // ---- coalesced v copy-out ----
#pragma unroll
    for (int r = 0; r < 16; ++r) {
        int i = t + (r << 8);
        int dv = i >> 6, tok = i & 63;
        u32 p = vst[dv * 65 + tok];
        long o = ((long)b * 64 + dv) * 1024 + n0 + tok;
        vth[o] = (u16)(p & 0xFFFFu);
        vtl[o] = (u16)(p >> 16);
    }
}

// ---------------------------------------------------------------------------
// MFMA flash attention, d_qk = 128, packed u32 q/k planes.
// LDS pitches: K 136 u16 (272B, 16B-aligned, dword-stride 68 = 4 mod 32);
// V 40 u16 (80B, aligned). QK 24 MFMA + PV 8 MFMA per 32-key iter.
// ---------------------------------------------------------------------------
__global__ __launch_bounds__(256, 2) void attn_kernel(
    const u32* __restrict__ qhl, const u32* __restrict__ khl,
    const u16* __restrict__ vth, const u16* __restrict__ vtl,
    float* __restrict__ out)
{
    __shared__ u16 KH[2 * 32 * 136];
    __shared__ u16 KL[2 * 32 * 136];
    __shared__ u16 VH[2 * 64 * 40];
    __shared__ u16 VL[2 * 64 * 40];

    const int t = threadIdx.x;
    const int lane = t & 63;
    const int w = t >> 6;
    const int l31 = lane & 31, g = lane >> 5;

    const int bid = blockIdx.x;
    const int b = ((bid & 7) << 3) + (bid >> 6);
    const int qt = (bid >> 3) & 7;

    // ---- Q fragments (unpack packed u32 plane once) ----
    const long qtok = (long)b * 1024 + qt * 128 + w * 32 + l31;
    const u32* qp = qhl + qtok * 128 + g * 8;
    bf16x8 Qh[8], Ql[8];
#pragma unroll
    for (int c = 0; c < 8; ++c) {
        u32 pv[8];
        *(int4*)&pv[0] = *(const int4*)(qp + c * 16);
        *(int4*)&pv[4] = *(const int4*)(qp + c * 16 + 4);
#pragma unroll
        for (int e = 0; e < 8; ++e) {
            Qh[c][e] = (short)(pv[e] & 0xFFFFu);
            Ql[c][e] = (short)(pv[e] >> 16);
        }
    }

    const int skk = t >> 3, scs = t & 7;
    const u32* k_g = khl + ((long)b * 1024 + skk) * 128 + scs * 16;
    const int sdv = t >> 2, ssg = t & 3;
    const u16* vh_g = vth + ((long)b * 64 + sdv) * 1024 + ssg * 8;
    const u16* vl_g = vtl + ((long)b * 64 + sdv) * 1024 + ssg * 8;
    u16* kh_d = KH + skk * 136 + scs * 16;
    u16* kl_d = KL + skk * 136 + scs * 16;
    u16* vh_d = VH + sdv * 40 + ssg * 8;
    u16* vl_d = VL + sdv * 40 + ssg * 8;

    u32 kp[16];
    int4 rc0, rd0;

#define LOADT(kt) do { \
        const u32* p1 = k_g + (long)(kt) * 128; \
        *(int4*)&kp[0]  = *(const int4*)(p1); \
        *(int4*)&kp[4]  = *(const int4*)(p1 + 4); \
        *(int4*)&kp[8]  = *(const int4*)(p1 + 8); \
        *(int4*)&kp[12] = *(const int4*)(p1 + 12); \
        rc0 = *(const int4*)(vh_g + (kt)); \
        rd0 = *(const int4*)(vl_g + (kt)); \
    } while (0)

#define WRITET(buf) do { \
        u32 hh[8], ll[8]; \
        _Pragma("unroll") \
        for (int e = 0; e < 8; ++e) { \
            hh[e] = (kp[2*e] & 0xFFFFu) | (kp[2*e+1] << 16); \
            ll[e] = (kp[2*e] >> 16) | (kp[2*e+1] & 0xFFFF0000u); \
        } \
        u16* d1 = kh_d + (buf) * 4352; \
        *(int4*)(d1) = *(int4*)&hh[0]; *(int4*)(d1 + 8) = *(int4*)&hh[4]; \
        u16* d2 = kl_d + (buf) * 4352; \
        *(int4*)(d2) = *(int4*)&ll[0]; *(int4*)(d2 + 8) = *(int4*)&ll[4]; \
        *(int4*)(vh_d + (buf) * 2560) = rc0; \
        *(int4*)(vl_d + (buf) * 2560) = rd0; \
    } while (0)

    f32x16 o0, o1;
#pragma unroll
    for (int r = 0; r < 16; ++r) { o0[r] = 0.f; o1[r] = 0.f; }
    float m_run = -1e30f, l_run = 0.f;

    LOADT(0);
    WRITET(0);
    __syncthreads();

    for (int it = 0; it < 32; ++it) {
        const int cb = it & 1;
        if (it < 31) LOADT((it + 1) * 32);

        // ---- QK^T (swapped): S^T[key][q], hi/lo passes ----
        f32x16 sA, sB;
#pragma unroll
        for (int r = 0; r < 16; ++r) { sA[r] = 0.f; sB[r] = 0.f; }
        const u16* krh = KH + cb * 4352 + l31 * 136 + g * 8;
        const u16* krl = KL + cb * 4352 + l31 * 136 + g * 8;
        __builtin_amdgcn_s_setprio(1);
#pragma unroll
        for (int c = 0; c < 8; ++c) {
            bf16x8 fh = *(const bf16x8*)(krh + c * 16);
            bf16x8 fl = *(const bf16x8*)(krl + c * 16);
            sA = MFMA32(fh, Qh[c], sA);
            sB = MFMA32(fh, Ql[c], sB);
            sB = MFMA32(fl, Qh[c], sB);
        }
        __builtin_amdgcn_s_setprio(0);

        // ---- online softmax with defer-max ----
        float s[16];
#pragma unroll
        for (int r = 0; r < 16; ++r) s[r] = sA[r] + sB[r];
        float mt = s[0];
#pragma unroll
        for (int r = 1; r < 16; ++r) mt = fmaxf(mt, s[r]);
        mt = fmaxf(mt, __shfl_xor(mt, 32));
        if (!__all(mt - m_run <= 8.f)) {
            float mn = fmaxf(m_run, mt);
            float corr = __expf(m_run - mn);
            l_run *= corr;
#pragma unroll
            for (int r = 0; r < 16; ++r) { o0[r] *= corr; o1[r] *= corr; }
            m_run = mn;
        }
        float ps = 0.f;
#pragma unroll
        for (int r = 0; r < 16; ++r) { s[r] = __expf(s[r] - m_run); ps += s[r]; }
        ps += __shfl_xor(ps, 32);
        l_run += ps;

        bf16x8 ph0, ph1;
#pragma unroll
        for (int e = 0; e < 8; ++e) {
            ph0[e] = (short)f2bf(s[e]);
            ph1[e] = (short)f2bf(s[8 + e]);
        }

        // ---- PV: out^T[dv][q] += V^T · P^T (ph*vh + ph*vl) ----
        const u16* vbh = VH + cb * 2560;
        const u16* vbl = VL + cb * 2560;
        __builtin_amdgcn_s_setprio(1);
#pragma unroll
        for (int d = 0; d < 2; ++d) {
            f32x16 acc = d ? o1 : o0;
#pragma unroll
            for (int c = 0; c < 2; ++c) {
                const u16* ph_ = vbh + (d * 32 + l31) * 40 + c * 16 + g * 4;
                const u16* pl_ = vbl + (d * 32 + l31) * 40 + c * 16 + g * 4;
                bf16x4 h0 = *(const bf16x4*)(ph_);
                bf16x4 h1 = *(const bf16x4*)(ph_ + 8);
                bf16x4 l0 = *(const bf16x4*)(pl_);
                bf16x4 l1 = *(const bf16x4*)(pl_ + 8);
                bf16x8 vh8 = __builtin_shufflevector(h0, h1, 0, 1, 2, 3, 4, 5, 6, 7);
                bf16x8 vl8 = __builtin_shufflevector(l0, l1, 0, 1, 2, 3, 4, 5, 6, 7);
                bf16x8 pc = c ? ph1 : ph0;
                acc = MFMA32(vh8, pc, acc);
                acc = MFMA32(vl8, pc, acc);
            }
            if (d) o1 = acc; else o0 = acc;
        }
        __builtin_amdgcn_s_setprio(0);

        if (it < 31) WRITET(cb ^ 1);
        __syncthreads();
    }

    // ---- epilogue ----
    float inv = 1.0f / l_run;
    float* op = out + qtok * 64;
#pragma unroll
    for (int d = 0; d < 2; ++d) {
#pragma unroll
        for (int sg = 0; sg < 4; ++sg) {
            float4 o4;
            if (d == 0) o4 = make_float4(o0[4*sg+0]*inv, o0[4*sg+1]*inv, o0[4*sg+2]*inv, o0[4*sg+3]*inv);
            else        o4 = make_float4(o1[4*sg+0]*inv, o1[4*sg+1]*inv, o1[4*sg+2]*inv, o1[4*sg+3]*inv);
            *(float4*)(op + d * 32 + sg * 8 + g * 4) = o4;
        }
    }
#undef LOADT
#undef WRITET
}

extern "C" void kernel_launch(void* const* d_in, const int* in_sizes, int n_in,
                              void* d_out, int out_size, void* d_ws, size_t ws_size,
                              hipStream_t stream) {
    const float* vectors = (const float*)d_in[0];
    const float* scalars = (const float*)d_in[1];
    const float* Wq   = (const float*)d_in[2];
    const float* Wq_s = (const float*)d_in[3];
    const float* bq_s = (const float*)d_in[4];
    const float* Wk   = (const float*)d_in[5];
    const float* Wk_s = (const float*)d_in[6];
    const float* bk_s = (const float*)d_in[7];
    const float* Wv   = (const float*)d_in[8];
    float* o = (float*)d_out;

    u32* qhl = (u32*)d_ws;                 // 64*1024*128 u32
    u32* khl = qhl + 8388608;
    u16* vth = (u16*)(khl + 8388608);      // 64*64*1024 u16 each
    u16* vtl = vth + 4194304;

    prep_kernel<<<1024, 256, 0, stream>>>(vectors, scalars, Wq, Wq_s, bq_s,
                                          Wk, Wk_s, bk_s, Wv,
                                          qhl, khl, vth, vtl);
    attn_kernel<<<512, 256, 0, stream>>>(qhl, khl, vth, vtl, o);
}

// Round 6
// 132.008 us; speedup vs baseline: 3.0121x; 1.3784x over previous
//
#include <hip/hip_runtime.h>
#include <math.h>

typedef float f32x16 __attribute__((ext_vector_type(16)));
typedef short bf16x8 __attribute__((ext_vector_type(8)));
typedef short bf16x4 __attribute__((ext_vector_type(4)));
typedef unsigned short u16;
typedef unsigned int u32;

#define MFMA32(a, b, c) __builtin_amdgcn_mfma_f32_32x32x16_bf16(a, b, c, 0, 0, 0)

__device__ __forceinline__ u16 f2bf(float x) {
    u32 u = __float_as_uint(x);
    u += 0x7FFFu + ((u >> 16) & 1u);
    return (u16)(u >> 16);
}
__device__ __forceinline__ float bf2f(u16 h) {
    return __uint_as_float(((u32)h) << 16);
}
__device__ __forceinline__ u32 packhl(float x) {
    u16 h = f2bf(x);
    u16 l = f2bf(x - bf2f(h));
    return (u32)h | ((u32)l << 16);
}

// ---------------------------------------------------------------------------
// prep v6:
//   waves 0/1: vector features (q copy*SC + V; k = metric*G@u, G=Wq^T Wk)
//   waves 2/3: scalar projections as MFMA GEMM (A = scalar rows from global,
//              B = W rows from global, both hi/lo split in-reg; 12 MFMA/tile,
//              C cols = features -> coalesced packed-u32 stores)
// Outputs: qhl/khl u32 planes [tok][128] (hi|lo<<16); vth/vtl [b][dv][1024].
// ---------------------------------------------------------------------------
__global__ __launch_bounds__(256) void prep_kernel(
    const float* __restrict__ vectors, const float* __restrict__ scalars,
    const float* __restrict__ Wq, const float* __restrict__ Wq_s, const float* __restrict__ bq_s,
    const float* __restrict__ Wk, const float* __restrict__ Wk_s, const float* __restrict__ bk_s,
    const float* __restrict__ Wv,
    u32* __restrict__ qhl, u32* __restrict__ khl,
    u16* __restrict__ vth, u16* __restrict__ vtl)
{
    __shared__ float vl[64 * 68];    // normalized vectors [tok][64]
    __shared__ u32 vst[64 * 65];     // v staging [dv][tok], hi|lo<<16
    __shared__ float wls[1024];      // Wq (512) | Wk (512)

    const int t = threadIdx.x;
    const int lane = t & 63;
    const int w = t >> 6;
    const int b = blockIdx.x >> 4;
    const int n0 = (blockIdx.x & 15) << 6;
    const long tok0 = (long)b * 1024 + n0;
    const float SC = 0.07216878364870323f;   // 1/sqrt(192)

    // ---- stage vectors + weight LDS (all waves) ----
    const float4* vin = (const float4*)(vectors + tok0 * 64);
#pragma unroll
    for (int r = 0; r < 4; ++r) {
        int i4 = t + (r << 8);
        int tok = i4 >> 4, c4 = (i4 & 15) << 2;
        *(float4*)&vl[tok * 68 + c4] = vin[i4];
    }
    for (int i = t; i < 1024; i += 256) wls[i] = (i < 512) ? Wq[i] : Wk[i - 512];
    __syncthreads();

    // ---- Lorentz normalize in place (all waves) ----
#pragma unroll
    for (int r = 0; r < 4; ++r) {
        int gi = t + (r << 8);
        float* p = &vl[(gi >> 4) * 68 + ((gi & 15) << 2)];
        float x0 = p[0], x1 = p[1], x2 = p[2], x3 = p[3];
        float nrm = x0 * x0 - x1 * x1 - x2 * x2 - x3 * x3;
        float inv = 1.0f / sqrtf(fmaxf(fabsf(nrm), 1e-5f));
        p[0] = x0 * inv; p[1] = x1 * inv; p[2] = x2 * inv; p[3] = x3 * inv;
    }
    __syncthreads();

    if (w == 0) {
        // q vec feature = lane (normalized vec * SC); V feature = lane
        float wrv[16];
#pragma unroll
        for (int j = 0; j < 16; ++j) wrv[j] = expf(Wv[(lane >> 2) * 16 + j]);
        const int vc = lane & 3;
        for (int tok = 0; tok < 64; ++tok) {
            qhl[(tok0 + tok) * 128 + lane] = packhl(vl[tok * 68 + lane] * SC);
            const float* p0 = &vl[tok * 68 + vc];
            float a0 = 0.f, a1 = 0.f, a2 = 0.f, a3 = 0.f;
#pragma unroll
            for (int j = 0; j < 16; j += 4) {
                a0 = fmaf(wrv[j],     p0[j * 4],       a0);
                a1 = fmaf(wrv[j + 1], p0[(j + 1) * 4], a1);
                a2 = fmaf(wrv[j + 2], p0[(j + 2) * 4], a2);
                a3 = fmaf(wrv[j + 3], p0[(j + 3) * 4], a3);
            }
            vst[lane * 65 + tok] = packhl((a0 + a1) + (a2 + a3));
        }
    } else if (w == 1) {
        // k vec: gr[jp] = m_c * (Wq^T Wk)[i,jp]
        const int i_ = lane >> 2, c = lane & 3;
        const float mc = (c == 0) ? 1.f : -1.f;
        float wqc[32];
#pragma unroll
        for (int f = 0; f < 32; ++f) wqc[f] = wls[f * 16 + i_];
        float gr[16];
#pragma unroll
        for (int jp = 0; jp < 16; ++jp) {
            float a0 = 0.f, a1 = 0.f;
#pragma unroll
            for (int f = 0; f < 32; f += 2) {
                a0 = fmaf(wqc[f],     wls[512 + f * 16 + jp],       a0);
                a1 = fmaf(wqc[f + 1], wls[512 + (f + 1) * 16 + jp], a1);
            }
            gr[jp] = (a0 + a1) * mc;
        }
        for (int tok = 0; tok < 64; ++tok) {
            const float* p0 = &vl[tok * 68 + c];
            float a0 = 0.f, a1 = 0.f, a2 = 0.f, a3 = 0.f;
#pragma unroll
            for (int jp = 0; jp < 16; jp += 4) {
                a0 = fmaf(gr[jp],     p0[jp * 4],       a0);
                a1 = fmaf(gr[jp + 1], p0[(jp + 1) * 4], a1);
                a2 = fmaf(gr[jp + 2], p0[(jp + 2) * 4], a2);
                a3 = fmaf(gr[jp + 3], p0[(jp + 3) * 4], a3);
            }
            khl[(tok0 + tok) * 128 + lane] = packhl((a0 + a1) + (a2 + a3));
        }
    } else {
        // ---- scalar projections via MFMA: 32 tokens x {q64, k64} features ----
        const int tokbase = (w == 2) ? 0 : 32;
        const int l31 = lane & 31, g = lane >> 5;

        // A fragments: this lane's token scalar row, hi/lo split
        bf16x8 Ah[4], Al[4];
        const float* xrow = scalars + (tok0 + tokbase + l31) * 64 + g * 8;
#pragma unroll
        for (int kk = 0; kk < 4; ++kk) {
            float4 x0 = *(const float4*)(xrow + kk * 16);
            float4 x1 = *(const float4*)(xrow + kk * 16 + 4);
            float xs[8] = {x0.x, x0.y, x0.z, x0.w, x1.x, x1.y, x1.z, x1.w};
#pragma unroll
            for (int e = 0; e < 8; ++e) {
                u16 h = f2bf(xs[e]);
                Ah[kk][e] = (short)h;
                Al[kk][e] = (short)f2bf(xs[e] - bf2f(h));
            }
        }

#pragma unroll
        for (int ft = 0; ft < 4; ++ft) {
            const int isq = (ft < 2);
            const int fs = ((ft & 1) << 5) + l31;
            const float* wrow = (isq ? Wq_s : Wk_s) + fs * 64 + g * 8;
            f32x16 acc;
#pragma unroll
            for (int r = 0; r < 16; ++r) acc[r] = 0.f;
#pragma unroll
            for (int kk = 0; kk < 4; ++kk) {
                float4 w0_ = *(const float4*)(wrow + kk * 16);
                float4 w1_ = *(const float4*)(wrow + kk * 16 + 4);
                float ws_[8] = {w0_.x, w0_.y, w0_.z, w0_.w, w1_.x, w1_.y, w1_.z, w1_.w};
                bf16x8 Bh, Bl;
#pragma unroll
                for (int e = 0; e < 8; ++e) {
                    u16 h = f2bf(ws_[e]);
                    Bh[e] = (short)h;
                    Bl[e] = (short)f2bf(ws_[e] - bf2f(h));
                }
                acc = MFMA32(Ah[kk], Bh, acc);
                acc = MFMA32(Ah[kk], Bl, acc);
                acc = MFMA32(Al[kk], Bh, acc);
            }
            const float bias = (isq ? bq_s : bk_s)[fs];
            const float sc = isq ? SC : 1.f;
            u32* oplane = isq ? qhl : khl;
#pragma unroll
            for (int reg = 0; reg < 16; ++reg) {
                int trow = (reg & 3) + 8 * (reg >> 2) + 4 * g;
                float val = (acc[reg] + bias) * sc;
                oplane[(tok0 + tokbase + trow) * 128 + 64 + fs] = packhl(val);
            }
        }
    }
    __syncthreads();

    // ---- coalesced v copy-out (all waves) ----
#pragma unroll
    for (int r = 0; r < 16; ++r) {
        int i = t + (r << 8);
        int dv = i >> 6, tok = i & 63;
        u32 p = vst[dv * 65 + tok];
        long o = ((long)b * 64 + dv) * 1024 + n0 + tok;
        vth[o] = (u16)(p & 0xFFFFu);
        vtl[o] = (u16)(p >> 16);
    }
}

// ---------------------------------------------------------------------------
// MFMA flash attention, d_qk = 128, packed u32 q/k planes. (unchanged)
// ---------------------------------------------------------------------------
__global__ __launch_bounds__(256, 2) void attn_kernel(
    const u32* __restrict__ qhl, const u32* __restrict__ khl,
    const u16* __restrict__ vth, const u16* __restrict__ vtl,
    float* __restrict__ out)
{
    __shared__ u16 KH[2 * 32 * 136];
    __shared__ u16 KL[2 * 32 * 136];
    __shared__ u16 VH[2 * 64 * 40];
    __shared__ u16 VL[2 * 64 * 40];

    const int t = threadIdx.x;
    const int lane = t & 63;
    const int w = t >> 6;
    const int l31 = lane & 31, g = lane >> 5;

    const int bid = blockIdx.x;
    const int b = ((bid & 7) << 3) + (bid >> 6);
    const int qt = (bid >> 3) & 7;

    const long qtok = (long)b * 1024 + qt * 128 + w * 32 + l31;
    const u32* qp = qhl + qtok * 128 + g * 8;
    bf16x8 Qh[8], Ql[8];
#pragma unroll
    for (int c = 0; c < 8; ++c) {
        u32 pv[8];
        *(int4*)&pv[0] = *(const int4*)(qp + c * 16);
        *(int4*)&pv[4] = *(const int4*)(qp + c * 16 + 4);
#pragma unroll
        for (int e = 0; e < 8; ++e) {
            Qh[c][e] = (short)(pv[e] & 0xFFFFu);
            Ql[c][e] = (short)(pv[e] >> 16);
        }
    }

    const int skk = t >> 3, scs = t & 7;
    const u32* k_g = khl + ((long)b * 1024 + skk) * 128 + scs * 16;
    const int sdv = t >> 2, ssg = t & 3;
    const u16* vh_g = vth + ((long)b * 64 + sdv) * 1024 + ssg * 8;
    const u16* vl_g = vtl + ((long)b * 64 + sdv) * 1024 + ssg * 8;
    u16* kh_d = KH + skk * 136 + scs * 16;
    u16* kl_d = KL + skk * 136 + scs * 16;
    u16* vh_d = VH + sdv * 40 + ssg * 8;
    u16* vl_d = VL + sdv * 40 + ssg * 8;

    u32 kp[16];
    int4 rc0, rd0;

#define LOADT(kt) do { \
        const u32* p1 = k_g + (long)(kt) * 128; \
        *(int4*)&kp[0]  = *(const int4*)(p1); \
        *(int4*)&kp[4]  = *(const int4*)(p1 + 4); \
        *(int4*)&kp[8]  = *(const int4*)(p1 + 8); \
        *(int4*)&kp[12] = *(const int4*)(p1 + 12); \
        rc0 = *(const int4*)(vh_g + (kt)); \
        rd0 = *(const int4*)(vl_g + (kt)); \
    } while (0)

#define WRITET(buf) do { \
        u32 hh[8], ll[8]; \
        _Pragma("unroll") \
        for (int e = 0; e < 8; ++e) { \
            hh[e] = (kp[2*e] & 0xFFFFu) | (kp[2*e+1] << 16); \
            ll[e] = (kp[2*e] >> 16) | (kp[2*e+1] & 0xFFFF0000u); \
        } \
        u16* d1 = kh_d + (buf) * 4352; \
        *(int4*)(d1) = *(int4*)&hh[0]; *(int4*)(d1 + 8) = *(int4*)&hh[4]; \
        u16* d2 = kl_d + (buf) * 4352; \
        *(int4*)(d2) = *(int4*)&ll[0]; *(int4*)(d2 + 8) = *(int4*)&ll[4]; \
        *(int4*)(vh_d + (buf) * 2560) = rc0; \
        *(int4*)(vl_d + (buf) * 2560) = rd0; \
    } while (0)

    f32x16 o0, o1;
#pragma unroll
    for (int r = 0; r < 16; ++r) { o0[r] = 0.f; o1[r] = 0.f; }
    float m_run = -1e30f, l_run = 0.f;

    LOADT(0);
    WRITET(0);
    __syncthreads();

    for (int it = 0; it < 32; ++it) {
        const int cb = it & 1;
        if (it < 31) LOADT((it + 1) * 32);

        f32x16 sA, sB;
#pragma unroll
        for (int r = 0; r < 16; ++r) { sA[r] = 0.f; sB[r] = 0.f; }
        const u16* krh = KH + cb * 4352 + l31 * 136 + g * 8;
        const u16* krl = KL + cb * 4352 + l31 * 136 + g * 8;
        __builtin_amdgcn_s_setprio(1);
#pragma unroll
        for (int c = 0; c < 8; ++c) {
            bf16x8 fh = *(const bf16x8*)(krh + c * 16);
            bf16x8 fl = *(const bf16x8*)(krl + c * 16);
            sA = MFMA32(fh, Qh[c], sA);
            sB = MFMA32(fh, Ql[c], sB);
            sB = MFMA32(fl, Qh[c], sB);
        }
        __builtin_amdgcn_s_setprio(0);

        float s[16];
#pragma unroll
        for (int r = 0; r < 16; ++r) s[r] = sA[r] + sB[r];
        float mt = s[0];
#pragma unroll
        for (int r = 1; r < 16; ++r) mt = fmaxf(mt, s[r]);
        mt = fmaxf(mt, __shfl_xor(mt, 32));
        if (!__all(mt - m_run <= 8.f)) {
            float mn = fmaxf(m_run, mt);
            float corr = __expf(m_run - mn);
            l_run *= corr;
#pragma unroll
            for (int r = 0; r < 16; ++r) { o0[r] *= corr; o1[r] *= corr; }
            m_run = mn;
        }
        float ps = 0.f;
#pragma unroll
        for (int r = 0; r < 16; ++r) { s[r] = __expf(s[r] - m_run); ps += s[r]; }
        ps += __shfl_xor(ps, 32);
        l_run += ps;

        bf16x8 ph0, ph1;
#pragma unroll
        for (int e = 0; e < 8; ++e) {
            ph0[e] = (short)f2bf(s[e]);
            ph1[e] = (short)f2bf(s[8 + e]);
        }

        const u16* vbh = VH + cb * 2560;
        const u16* vbl = VL + cb * 2560;
        __builtin_amdgcn_s_setprio(1);
#pragma unroll
        for (int d = 0; d < 2; ++d) {
            f32x16 acc = d ? o1 : o0;
#pragma unroll
            for (int c = 0; c < 2; ++c) {
                const u16* ph_ = vbh + (d * 32 + l31) * 40 + c * 16 + g * 4;
                const u16* pl_ = vbl + (d * 32 + l31) * 40 + c * 16 + g * 4;
                bf16x4 h0 = *(const bf16x4*)(ph_);
                bf16x4 h1 = *(const bf16x4*)(ph_ + 8);
                bf16x4 l0 = *(const bf16x4*)(pl_);
                bf16x4 l1 = *(const bf16x4*)(pl_ + 8);
                bf16x8 vh8 = __builtin_shufflevector(h0, h1, 0, 1, 2, 3, 4, 5, 6, 7);
                bf16x8 vl8 = __builtin_shufflevector(l0, l1, 0, 1, 2, 3, 4, 5, 6, 7);
                bf16x8 pc = c ? ph1 : ph0;
                acc = MFMA32(vh8, pc, acc);
                acc = MFMA32(vl8, pc, acc);
            }
            if (d) o1 = acc; else o0 = acc;
        }
        __builtin_amdgcn_s_setprio(0);

        if (it < 31) WRITET(cb ^ 1);
        __syncthreads();
    }

    float inv = 1.0f / l_run;
    float* op = out + qtok * 64;
#pragma unroll
    for (int d = 0; d < 2; ++d) {
#pragma unroll
        for (int sg = 0; sg < 4; ++sg) {
            float4 o4;
            if (d == 0) o4 = make_float4(o0[4*sg+0]*inv, o0[4*sg+1]*inv, o0[4*sg+2]*inv, o0[4*sg+3]*inv);
            else        o4 = make_float4(o1[4*sg+0]*inv, o1[4*sg+1]*inv, o1[4*sg+2]*inv, o1[4*sg+3]*inv);
            *(float4*)(op + d * 32 + sg * 8 + g * 4) = o4;
        }
    }
#undef LOADT
#undef WRITET
}

extern "C" void kernel_launch(void* const* d_in, const int* in_sizes, int n_in,
                              void* d_out, int out_size, void* d_ws, size_t ws_size,
                              hipStream_t stream) {
    const float* vectors = (const float*)d_in[0];
    const float* scalars = (const float*)d_in[1];
    const float* Wq   = (const float*)d_in[2];
    const float* Wq_s = (const float*)d_in[3];
    const float* bq_s = (const float*)d_in[4];
    const float* Wk   = (const float*)d_in[5];
    const float* Wk_s = (const float*)d_in[6];
    const float* bk_s = (const float*)d_in[7];
    const float* Wv   = (const float*)d_in[8];
    float* o = (float*)d_out;

    u32* qhl = (u32*)d_ws;                 // 64*1024*128 u32
    u32* khl = qhl + 8388608;
    u16* vth = (u16*)(khl + 8388608);      // 64*64*1024 u16 each
    u16* vtl = vth + 4194304;

    prep_kernel<<<1024, 256, 0, stream>>>(vectors, scalars, Wq, Wq_s, bq_s,
                                          Wk, Wk_s, bk_s, Wv,
                                          qhl, khl, vth, vtl);
    attn_kernel<<<512, 256, 0, stream>>>(qhl, khl, vth, vtl, o);
}